// Round 1
// baseline (1400.708 us; speedup 1.0000x reference)
//
#include <hip/hip_runtime.h>
#include <math.h>

#define B_  4
#define H_  16
#define S_  1024
#define DK_ 64

constexpr float SCALE = 0.125f;     // 1/sqrt(64)
constexpr float NEGV  = -1.0e9f;

#define RPW   2                     // query rows per wave (was 4)
#define WAVES 4
#define RPB   (RPW * WAVES)         // 8 rows per block
#define NT    (S_ / 64)             // 16 column tiles of 64
#define BPBH  (S_ / RPB)            // 128 blocks per (b,h)
#define NWG   (BPBH * B_ * H_)      // 8192 blocks, % 8 == 0

__device__ __forceinline__ float wave_max(float v) {
#pragma unroll
    for (int off = 32; off >= 1; off >>= 1)
        v = fmaxf(v, __shfl_xor(v, off, 64));
    return v;
}

__device__ __forceinline__ float wave_sum(float v) {
#pragma unroll
    for (int off = 32; off >= 1; off >>= 1)
        v += __shfl_xor(v, off, 64);
    return v;
}

// 32 KB LDS/block -> 5 blocks/CU (160 KB exactly); 20 waves/CU = 5 waves/SIMD.
__launch_bounds__(256, 5)
__global__ void mha_scores_softmax(const float* __restrict__ q,
                                   const float* __restrict__ k,
                                   const int*   __restrict__ mask,
                                   float* __restrict__ attn_out,
                                   float* __restrict__ scores_out)
{
    // Wave-private score stash: 4 waves x 2 rows x 1024 cols x 4B = 32 KB.
    // Each wave only touches its own [w] slice -> NO __syncthreads needed.
    __shared__ float sc[WAVES][RPW][S_];

    // XCD-aware bijective swizzle: consecutive dispatch ids round-robin the
    // 8 XCDs; remap so each XCD owns a contiguous (bh, rowblock) range ->
    // K for a head stays resident in ONE XCD's L2.
    const int bid = blockIdx.x;
    const int swz = (bid & 7) * (NWG / 8) + (bid >> 3);
    const int bh  = swz / BPBH;                  // 0..63
    const int rb  = swz & (BPBH - 1);            // 0..127
    const int b   = bh >> 4;
    const int lane = threadIdx.x & 63;
    const int w    = __builtin_amdgcn_readfirstlane(threadIdx.x >> 6);
    const int row0 = rb * RPB + w * RPW;

    const float* qbase = q + ((size_t)bh * S_ + row0) * DK_;   // wave-uniform
    const float* kbase = k + (size_t)bh * S_ * DK_;
    const int*   mbase = mask + ((size_t)b * S_ + row0) * S_;
    float* srow = scores_out + ((size_t)bh * S_ + row0) * S_;
    float* arow = attn_out   + ((size_t)bh * S_ + row0) * S_;

    float mx[RPW];
#pragma unroll
    for (int r = 0; r < RPW; ++r) mx[r] = -INFINITY;

    // ---- Phase A: scores = mask(QK^T * scale); write global + LDS; track max ----
    for (int t = 0; t < NT; ++t) {
        const int col = (t << 6) + lane;
        const float* kp = kbase + (size_t)col * DK_;
        float acc[RPW];
#pragma unroll
        for (int r = 0; r < RPW; ++r) acc[r] = 0.0f;

#pragma unroll
        for (int ds = 0; ds < DK_ / 4; ++ds) {
            const float4 kv = *(const float4*)(kp + (ds << 2));
#pragma unroll
            for (int r = 0; r < RPW; ++r) {
                // wave-uniform address -> scalar (s_load) on the SMEM pipe
                const float4 qv = *(const float4*)(qbase + r * DK_ + (ds << 2));
                acc[r] = fmaf(qv.x, kv.x, acc[r]);
                acc[r] = fmaf(qv.y, kv.y, acc[r]);
                acc[r] = fmaf(qv.z, kv.z, acc[r]);
                acc[r] = fmaf(qv.w, kv.w, acc[r]);
            }
        }

#pragma unroll
        for (int r = 0; r < RPW; ++r) {
            const int mv = mbase[(size_t)r * S_ + col];
            float sv = acc[r] * SCALE;
            sv = (mv == 0) ? NEGV : sv;
            srow[(size_t)r * S_ + col] = sv;   // coalesced stream-out
            sc[w][r][col] = sv;                // LDS stash (2-way bank alias = free)
            mx[r] = fmaxf(mx[r], sv);
        }
    }

    float m[RPW], l[RPW];
#pragma unroll
    for (int r = 0; r < RPW; ++r) { m[r] = wave_max(mx[r]); l[r] = 0.0f; }

    // ---- Phase A2: p = exp(s - m); overwrite stash with p; accumulate l ----
    for (int t = 0; t < NT; ++t) {
        const int col = (t << 6) + lane;
#pragma unroll
        for (int r = 0; r < RPW; ++r) {
            const float p = __expf(sc[w][r][col] - m[r]);
            sc[w][r][col] = p;
            l[r] += p;
        }
    }

    float inv[RPW];
#pragma unroll
    for (int r = 0; r < RPW; ++r) inv[r] = 1.0f / wave_sum(l[r]);

    // ---- Phase B: attn = p * inv (exp already done in A2) ----
    for (int t = 0; t < NT; ++t) {
        const int col = (t << 6) + lane;
#pragma unroll
        for (int r = 0; r < RPW; ++r)
            arow[(size_t)r * S_ + col] = sc[w][r][col] * inv[r];
    }
}

extern "C" void kernel_launch(void* const* d_in, const int* in_sizes, int n_in,
                              void* d_out, int out_size, void* d_ws, size_t ws_size,
                              hipStream_t stream) {
    const float* q    = (const float*)d_in[0];
    const float* k    = (const float*)d_in[1];
    // d_in[2] = value: unused by the reference outputs (attn, scores)
    const int*   mask = (const int*)d_in[3];

    float* out    = (float*)d_out;
    float* attn   = out;                                   // (B,H,S,S)
    float* scores = out + (size_t)B_ * H_ * S_ * S_;       // (B,H,S,S)

    mha_scores_softmax<<<dim3(NWG), dim3(256), 0, stream>>>(q, k, mask, attn, scores);
}

// Round 2
// 1018.006 us; speedup vs baseline: 1.3759x; 1.3759x over previous
//
#include <hip/hip_runtime.h>
#include <math.h>

#define B_  4
#define H_  16
#define S_  1024
#define DK_ 64

constexpr float SCALE = 0.125f;     // 1/sqrt(64)
constexpr float NEGV  = -1.0e9f;

#define RPW   4                     // query rows per wave
#define WAVES 4
#define RPB   (RPW * WAVES)         // 16 rows per block
#define NT    (S_ / 64)             // 16 K-tiles of 64 rows
#define BPBH  (S_ / RPB)            // 64 blocks per (b,h)
#define NWG   (BPBH * B_ * H_)      // 4096 blocks, % 8 == 0
#define KPAD  4                     // LDS row stride 68 floats (272 B) -> banks spread

typedef float f32x4 __attribute__((ext_vector_type(4)));

__device__ __forceinline__ float wave_max(float v) {
#pragma unroll
    for (int off = 32; off >= 1; off >>= 1)
        v = fmaxf(v, __shfl_xor(v, off, 64));
    return v;
}

__device__ __forceinline__ float wave_sum(float v) {
#pragma unroll
    for (int off = 32; off >= 1; off >>= 1)
        v += __shfl_xor(v, off, 64);
    return v;
}

// Pass 1: scores = mask(QK^T*scale) -> global; per-row {max, 1/sum} -> stash
// K staged coalesced into double-buffered LDS; per-lane online softmax (no score stash).
// LDS = 2*64*68*4 = 34 KB -> 4 blocks/CU (16 waves/CU).
__launch_bounds__(256, 4)
__global__ void mha_scores_pass1(const float* __restrict__ q,
                                 const float* __restrict__ k,
                                 const int*   __restrict__ mask,
                                 float* __restrict__ attn_ml,    // stash {M, invL} per row
                                 float* __restrict__ scores_out)
{
    __shared__ float kt[2][64][DK_ + KPAD];

    // XCD-aware bijective swizzle (4096 % 8 == 0): each XCD owns 8 heads ->
    // that XCD's L2 holds 8 x 256 KB of K.
    const int bid  = blockIdx.x;
    const int swz  = (bid & 7) * (NWG / 8) + (bid >> 3);
    const int bh   = swz >> 6;                  // 0..63
    const int rb   = swz & (BPBH - 1);          // 0..63
    const int b    = bh >> 4;
    const int u    = threadIdx.x;
    const int lane = u & 63;
    const int w    = __builtin_amdgcn_readfirstlane(u >> 6);
    const int row0 = rb * RPB + w * RPW;

    const float* qbase = q + ((size_t)bh * S_ + row0) * DK_;    // wave-uniform
    const float* kbase = k + (size_t)bh * S_ * DK_;
    const int*   mbase = mask + ((size_t)b * S_ + row0) * S_;
    float* srow = scores_out + ((size_t)bh * S_ + row0) * S_;
    float* aml  = attn_ml    + ((size_t)bh * S_ + row0) * S_;

    // staging map: thread u covers rows {p*16 + u/16}, d-block (u%16)*4
    const int strow = u >> 4;           // 0..15
    const int sd    = (u & 15) << 2;    // 0..60

    float4 pre[4];
#pragma unroll
    for (int p = 0; p < 4; ++p)
        pre[p] = *(const float4*)(kbase + (size_t)(p * 16 + strow) * DK_ + sd);
#pragma unroll
    for (int p = 0; p < 4; ++p)
        *(float4*)(&kt[0][p * 16 + strow][sd]) = pre[p];
    __syncthreads();

    float mx[RPW], l[RPW];
#pragma unroll
    for (int r = 0; r < RPW; ++r) { mx[r] = -INFINITY; l[r] = 0.0f; }

    for (int t = 0; t < NT; ++t) {
        const int cb = t & 1;
        // issue next tile's global loads early (hide HBM latency under compute)
        if (t + 1 < NT) {
#pragma unroll
            for (int p = 0; p < 4; ++p)
                pre[p] = *(const float4*)(kbase +
                          (size_t)((t + 1) * 64 + p * 16 + strow) * DK_ + sd);
        }

        const int col = (t << 6) + lane;
        int mv[RPW];
#pragma unroll
        for (int r = 0; r < RPW; ++r) mv[r] = mbase[(size_t)r * S_ + col];

        float acc[RPW] = {0.0f, 0.0f, 0.0f, 0.0f};
#pragma unroll
        for (int ds = 0; ds < DK_ / 4; ++ds) {
            // lane reads its own K-row slice: stride 272 B -> conflict-free b128
            const f32x4 kv = *(const f32x4*)(&kt[cb][lane][ds << 2]);
#pragma unroll
            for (int r = 0; r < RPW; ++r) {
                // wave-uniform -> s_load on scalar pipe, K$-hot across tiles
                const float4 qv = *(const float4*)(qbase + r * DK_ + (ds << 2));
                acc[r] = fmaf(qv.x, kv.x, acc[r]);
                acc[r] = fmaf(qv.y, kv.y, acc[r]);
                acc[r] = fmaf(qv.z, kv.z, acc[r]);
                acc[r] = fmaf(qv.w, kv.w, acc[r]);
            }
        }

#pragma unroll
        for (int r = 0; r < RPW; ++r) {
            float sv = acc[r] * SCALE;
            sv = (mv[r] == 0) ? NEGV : sv;
            srow[(size_t)r * S_ + col] = sv;            // coalesced, cached (pass 2 re-reads)
            // per-lane online softmax: branchless rescale
            const float mn = fmaxf(mx[r], sv);
            l[r] = fmaf(l[r], __expf(mx[r] - mn), __expf(sv - mn));
            mx[r] = mn;
        }

        if (t + 1 < NT) {
            const int nb = cb ^ 1;
#pragma unroll
            for (int p = 0; p < 4; ++p)
                *(float4*)(&kt[nb][p * 16 + strow][sd]) = pre[p];
        }
        __syncthreads();
    }

    // finalize: exact row max + denom across lanes; stash {M, 1/L} in attn row head
#pragma unroll
    for (int r = 0; r < RPW; ++r) {
        const float M = wave_max(mx[r]);
        const float L = wave_sum(l[r] * __expf(mx[r] - M));
        if (lane == 0)
            *(float2*)(aml + (size_t)r * S_) = make_float2(M, 1.0f / L);
    }
}

// Pass 2: attn = exp(s - M) * invL. Pure streaming, NT loads/stores.
__launch_bounds__(256, 8)
__global__ void mha_softmax_pass2(const float* __restrict__ scores,
                                  float* __restrict__ attn)
{
    const int lane = threadIdx.x & 63;
    const int w    = threadIdx.x >> 6;
    const size_t row = (size_t)blockIdx.x * 4 + w;      // 65536 rows, 1 per wave
    const float* srow = scores + row * S_;
    float*       arow = attn   + row * S_;

    // stash written by pass 1 at the head of this attn row; read before overwrite
    const float2 ml  = *(const float2*)(arow);
    const float  M   = ml.x;
    const float  inv = ml.y;

#pragma unroll
    for (int p = 0; p < 4; ++p) {
        const int c = (p << 8) + (lane << 2);
        const f32x4 s4 = __builtin_nontemporal_load((const f32x4*)(srow + c));
        f32x4 a4;
        a4.x = __expf(s4.x - M) * inv;
        a4.y = __expf(s4.y - M) * inv;
        a4.z = __expf(s4.z - M) * inv;
        a4.w = __expf(s4.w - M) * inv;
        __builtin_nontemporal_store(a4, (f32x4*)(arow + c));
    }
}

extern "C" void kernel_launch(void* const* d_in, const int* in_sizes, int n_in,
                              void* d_out, int out_size, void* d_ws, size_t ws_size,
                              hipStream_t stream) {
    const float* q    = (const float*)d_in[0];
    const float* k    = (const float*)d_in[1];
    // d_in[2] = value: unused by the reference outputs (attn, scores)
    const int*   mask = (const int*)d_in[3];

    float* out    = (float*)d_out;
    float* attn   = out;                                   // (B,H,S,S)
    float* scores = out + (size_t)B_ * H_ * S_ * S_;       // (B,H,S,S)

    mha_scores_pass1<<<dim3(NWG), dim3(256), 0, stream>>>(q, k, mask, attn, scores);
    mha_softmax_pass2<<<dim3((B_ * H_ * S_) / 4), dim3(256), 0, stream>>>(scores, attn);
}

// Round 3
// 1005.698 us; speedup vs baseline: 1.3928x; 1.0122x over previous
//
#include <hip/hip_runtime.h>
#include <math.h>

#define B_  4
#define H_  16
#define S_  1024
#define DK_ 64

constexpr float SCALE = 0.125f;     // 1/sqrt(64)
constexpr float NEGV  = -1.0e9f;

#define RPW   4                     // query rows per wave
#define WAVES 4
#define RPB   (RPW * WAVES)         // 16 rows per block
#define NT    (S_ / 64)             // 16 K-tiles of 64 rows
#define BPBH  (S_ / RPB)            // 64 blocks per (b,h)
#define NWG   (BPBH * B_ * H_)      // 4096 blocks, % 8 == 0
#define KPAD  4                     // row stride 68 floats: b128 reads 2-way/phase = free

typedef float f32x4 __attribute__((ext_vector_type(4)));

__device__ __forceinline__ float wave_max(float v) {
#pragma unroll
    for (int off = 32; off >= 1; off >>= 1)
        v = fmaxf(v, __shfl_xor(v, off, 64));
    return v;
}

__device__ __forceinline__ float wave_sum(float v) {
#pragma unroll
    for (int off = 32; off >= 1; off >>= 1)
        v += __shfl_xor(v, off, 64);
    return v;
}

// Pass 1: scores = mask(QK^T*scale) -> global; per-row {M, 1/L} -> stash.
// SINGLE-buffered K tile (17.4 KB LDS) + register prefetch (T14):
// 8 blocks/CU = 32 waves/CU = 100% occupancy (was 4 blocks / 45%).
__launch_bounds__(256, 8)
__global__ void mha_scores_pass1(const float* __restrict__ q,
                                 const float* __restrict__ k,
                                 const int*   __restrict__ mask,
                                 float* __restrict__ attn_ml,    // stash {M, invL} per row
                                 float* __restrict__ scores_out)
{
    __shared__ float kt[64][DK_ + KPAD];    // 17408 B

    // XCD-aware bijective swizzle (4096 % 8 == 0): each XCD owns 8 heads.
    const int bid  = blockIdx.x;
    const int swz  = (bid & 7) * (NWG / 8) + (bid >> 3);
    const int bh   = swz >> 6;                  // 0..63
    const int rb   = swz & (BPBH - 1);          // 0..63
    const int b    = bh >> 4;
    const int u    = threadIdx.x;
    const int lane = u & 63;
    const int w    = __builtin_amdgcn_readfirstlane(u >> 6);
    const int row0 = rb * RPB + w * RPW;

    const float* qbase = q + ((size_t)bh * S_ + row0) * DK_;    // wave-uniform -> s_load
    const float* kbase = k + (size_t)bh * S_ * DK_;
    const int*   mbase = mask + ((size_t)b * S_ + row0) * S_;
    float* srow = scores_out + ((size_t)bh * S_ + row0) * S_;
    float* aml  = attn_ml    + ((size_t)bh * S_ + row0) * S_;

    // staging map: thread u covers rows {p*16 + u/16}, d-block (u%16)*4
    const int strow = u >> 4;           // 0..15
    const int sd    = (u & 15) << 2;    // 0..60

    // ---- prologue: stage tile 0 ----
    float4 pre[4];
#pragma unroll
    for (int p = 0; p < 4; ++p)
        pre[p] = *(const float4*)(kbase + (size_t)(p * 16 + strow) * DK_ + sd);
#pragma unroll
    for (int p = 0; p < 4; ++p)
        *(float4*)(&kt[p * 16 + strow][sd]) = pre[p];
    __syncthreads();

    float mx[RPW], l[RPW];
#pragma unroll
    for (int r = 0; r < RPW; ++r) { mx[r] = -INFINITY; l[r] = 0.0f; }

    for (int t = 0; t < NT; ++t) {
        // issue next tile's global loads NOW; they stay in flight under this
        // tile's compute (vmcnt drained only at the ds_write after the barrier)
        if (t + 1 < NT) {
#pragma unroll
            for (int p = 0; p < 4; ++p)
                pre[p] = *(const float4*)(kbase +
                          (size_t)((t + 1) * 64 + p * 16 + strow) * DK_ + sd);
        }

        const int col = (t << 6) + lane;
        int mv[RPW];
#pragma unroll
        for (int r = 0; r < RPW; ++r) mv[r] = mbase[(size_t)r * S_ + col];

        float acc[RPW] = {0.0f, 0.0f, 0.0f, 0.0f};
#pragma unroll
        for (int ds = 0; ds < DK_ / 4; ++ds) {
            // per-lane K slice: stride 272 B, quarter-wave phases 2-way = free
            const f32x4 kv = *(const f32x4*)(&kt[lane][ds << 2]);
#pragma unroll
            for (int r = 0; r < RPW; ++r) {
                // wave-uniform -> scalar pipe (sK$-hot across the 16 tiles)
                const float4 qv = *(const float4*)(qbase + r * DK_ + (ds << 2));
                acc[r] = fmaf(qv.x, kv.x, acc[r]);
                acc[r] = fmaf(qv.y, kv.y, acc[r]);
                acc[r] = fmaf(qv.z, kv.z, acc[r]);
                acc[r] = fmaf(qv.w, kv.w, acc[r]);
            }
        }

#pragma unroll
        for (int r = 0; r < RPW; ++r) {
            float sv = acc[r] * SCALE;
            sv = (mv[r] == 0) ? NEGV : sv;
            srow[(size_t)r * S_ + col] = sv;            // coalesced stream-out
            // per-lane online softmax: branchless rescale
            const float mn = fmaxf(mx[r], sv);
            l[r] = fmaf(l[r], __expf(mx[r] - mn), __expf(sv - mn));
            mx[r] = mn;
        }

        if (t + 1 < NT) {
            __syncthreads();    // all waves done READING kt
#pragma unroll
            for (int p = 0; p < 4; ++p)
                *(float4*)(&kt[p * 16 + strow][sd]) = pre[p];
            __syncthreads();    // kt holds tile t+1
        }
    }

    // finalize: exact row max + denom; stash {M, 1/L} at attn row head
#pragma unroll
    for (int r = 0; r < RPW; ++r) {
        const float M = wave_max(mx[r]);
        const float L = wave_sum(l[r] * __expf(mx[r] - M));
        if (lane == 0)
            *(float2*)(aml + (size_t)r * S_) = make_float2(M, 1.0f / L);
    }
}

// Pass 2: attn = exp(s - M) * invL. Pure streaming.
__launch_bounds__(256, 8)
__global__ void mha_softmax_pass2(const float* __restrict__ scores,
                                  float* __restrict__ attn)
{
    const int lane = threadIdx.x & 63;
    const int w    = threadIdx.x >> 6;
    const size_t row = (size_t)blockIdx.x * 4 + w;      // 65536 rows, 1 per wave
    const float* srow = scores + row * S_;
    float*       arow = attn   + row * S_;

    // stash written by pass 1 at the head of this attn row; read before overwrite
    const float2 ml  = *(const float2*)(arow);
    const float  M   = ml.x;
    const float  inv = ml.y;

#pragma unroll
    for (int p = 0; p < 4; ++p) {
        const int c = (p << 8) + (lane << 2);
        const f32x4 s4 = __builtin_nontemporal_load((const f32x4*)(srow + c));
        f32x4 a4;
        a4.x = __expf(s4.x - M) * inv;
        a4.y = __expf(s4.y - M) * inv;
        a4.z = __expf(s4.z - M) * inv;
        a4.w = __expf(s4.w - M) * inv;
        __builtin_nontemporal_store(a4, (f32x4*)(arow + c));
    }
}

extern "C" void kernel_launch(void* const* d_in, const int* in_sizes, int n_in,
                              void* d_out, int out_size, void* d_ws, size_t ws_size,
                              hipStream_t stream) {
    const float* q    = (const float*)d_in[0];
    const float* k    = (const float*)d_in[1];
    // d_in[2] = value: unused by the reference outputs (attn, scores)
    const int*   mask = (const int*)d_in[3];

    float* out    = (float*)d_out;
    float* attn   = out;                                   // (B,H,S,S)
    float* scores = out + (size_t)B_ * H_ * S_ * S_;       // (B,H,S,S)

    mha_scores_pass1<<<dim3(NWG), dim3(256), 0, stream>>>(q, k, mask, attn, scores);
    mha_softmax_pass2<<<dim3((B_ * H_ * S_) / 4), dim3(256), 0, stream>>>(scores, attn);
}

// Round 4
// 807.544 us; speedup vs baseline: 1.7345x; 1.2454x over previous
//
#include <hip/hip_runtime.h>
#include <math.h>

#define B_  4
#define H_  16
#define S_  1024
#define DK_ 64

constexpr float SCALE = 0.125f;     // 1/sqrt(64)
constexpr float NEGV  = -1.0e9f;

#define RPW   4                     // query rows per wave
#define WAVES 4
#define RPB   (RPW * WAVES)         // 16 rows per block
#define NTL   (S_ / 64)             // 16 K-tiles of 64 rows
#define BPBH  (S_ / RPB)            // 64 blocks per (b,h)
#define NWG   (BPBH * B_ * H_)      // 4096 blocks, % 8 == 0

typedef float f32x4 __attribute__((ext_vector_type(4)));

__device__ __forceinline__ float wave_max(float v) {
#pragma unroll
    for (int off = 32; off >= 1; off >>= 1)
        v = fmaxf(v, __shfl_xor(v, off, 64));
    return v;
}

__device__ __forceinline__ float wave_sum(float v) {
#pragma unroll
    for (int off = 32; off >= 1; off >>= 1)
        v += __shfl_xor(v, off, 64);
    return v;
}

// Fused: scores = mask(QK^T*scale) -> NT store; softmax from REGISTER stash
// -> NT store. K double-buffered in LDS via async global_load_lds with
// XOR-swizzled storage (linear dest + pre-swizzled source + swizzled read).
// VGPR ~110 -> 4 waves/SIMD; LDS 32 KB -> 4 blocks/CU (128 KB).
__launch_bounds__(256, 4)
__global__ void mha_fused(const float* __restrict__ q,
                          const float* __restrict__ k,
                          const int*   __restrict__ mask,
                          float* __restrict__ attn_out,
                          float* __restrict__ scores_out)
{
    __shared__ float kt[2][64][DK_];    // 32 KB, swizzled: row r slot s holds d-group s^(r&7)

    // XCD swizzle, rb-major within XCD: co-resident blocks = same rb range x 8
    // heads of ONE batch -> mask rows reused 8x in L2; K per XCD = 2 MB.
    const int bid = blockIdx.x;
    const int xcd = bid & 7;
    const int idx = bid >> 3;           // 0..511
    const int hl  = idx & 7;            // head-within-xcd
    const int rb  = idx >> 3;           // 0..63
    const int bh  = xcd * 8 + hl;       // 0..63
    const int b   = bh >> 4;
    const int u    = threadIdx.x;
    const int lane = u & 63;
    const int w    = __builtin_amdgcn_readfirstlane(u >> 6);
    const int row0 = rb * RPB + w * RPW;

    const float* qbase = q + ((size_t)bh * S_ + row0) * DK_;    // wave-uniform -> s_load
    const float* kbase = k + (size_t)bh * S_ * DK_;
    const int*   mbase = mask + ((size_t)b * S_ + row0) * S_;
    float* srow = scores_out + ((size_t)bh * S_ + row0) * S_;
    float* arow = attn_out   + ((size_t)bh * S_ + row0) * S_;

    // async stage of one 64x64 K tile: 4 issues/wave, 1 KB each, linear LDS
    // dest (base + lane*16B); source d-group pre-swizzled so that LDS row r
    // slot s holds global d-group s^(r&7)  -> conflict-free b128 reads.
    auto stage = [&](int t, int bb) {
#pragma unroll
        for (int j = 0; j < 4; ++j) {
            const int quad = (w << 2) + j;              // 0..15 (4 rows each)
            const int qrow = (quad << 2) + (lane >> 4); // 0..63
            const int sl   = (lane & 15) ^ (qrow & 7);  // swizzled source slot
            const float* gp = kbase + (size_t)((t << 6) + qrow) * DK_ + (sl << 2);
            __builtin_amdgcn_global_load_lds(gp, &kt[bb][quad << 2][0], 16, 0, 0);
        }
    };

    float p[RPW][NTL];                  // per-lane score stash: 64 VGPRs
    float mx[RPW];
#pragma unroll
    for (int r = 0; r < RPW; ++r) mx[r] = -INFINITY;

    stage(0, 0);
    __syncthreads();                    // tile 0 resident

    // ---- Phase A: scores; stash in regs; track max ----
#pragma unroll
    for (int t = 0; t < NTL; ++t) {
        if (t + 1 < NTL) stage(t + 1, (t + 1) & 1);   // async, lands under compute

        const int col = (t << 6) + lane;
        int mv[RPW];
#pragma unroll
        for (int r = 0; r < RPW; ++r) mv[r] = mbase[(size_t)r * S_ + col];

        float acc[RPW] = {0.0f, 0.0f, 0.0f, 0.0f};
#pragma unroll
        for (int ds = 0; ds < DK_ / 4; ++ds) {
            // lane reads its row (=col) with XOR-swizzled slot: 2-way/phase = free
            const f32x4 kv = *(const f32x4*)(&kt[t & 1][lane][(ds ^ (lane & 7)) << 2]);
#pragma unroll
            for (int r = 0; r < RPW; ++r) {
                const float4 qv = *(const float4*)(qbase + r * DK_ + (ds << 2));
                acc[r] = fmaf(qv.x, kv.x, acc[r]);
                acc[r] = fmaf(qv.y, kv.y, acc[r]);
                acc[r] = fmaf(qv.z, kv.z, acc[r]);
                acc[r] = fmaf(qv.w, kv.w, acc[r]);
            }
        }

#pragma unroll
        for (int r = 0; r < RPW; ++r) {
            float sv = acc[r] * SCALE;
            sv = (mv[r] == 0) ? NEGV : sv;
            __builtin_nontemporal_store(sv, &srow[(size_t)r * S_ + col]);
            p[r][t] = sv;
            mx[r] = fmaxf(mx[r], sv);
        }

        // drain (stage t+1 done by all) + release buffer read this tile
        __syncthreads();
    }

    // ---- Phase A2: exact softmax over the register stash ----
    float M[RPW], l[RPW];
#pragma unroll
    for (int r = 0; r < RPW; ++r) { M[r] = wave_max(mx[r]); l[r] = 0.0f; }

#pragma unroll
    for (int t = 0; t < NTL; ++t)
#pragma unroll
        for (int r = 0; r < RPW; ++r) {
            const float e = __expf(p[r][t] - M[r]);
            p[r][t] = e;
            l[r] += e;
        }

    float inv[RPW];
#pragma unroll
    for (int r = 0; r < RPW; ++r) inv[r] = 1.0f / wave_sum(l[r]);

    // ---- Phase B: attn = p * inv, streamed ----
#pragma unroll
    for (int t = 0; t < NTL; ++t) {
        const int col = (t << 6) + lane;
#pragma unroll
        for (int r = 0; r < RPW; ++r)
            __builtin_nontemporal_store(p[r][t] * inv[r],
                                        &arow[(size_t)r * S_ + col]);
    }
}

extern "C" void kernel_launch(void* const* d_in, const int* in_sizes, int n_in,
                              void* d_out, int out_size, void* d_ws, size_t ws_size,
                              hipStream_t stream) {
    const float* q    = (const float*)d_in[0];
    const float* k    = (const float*)d_in[1];
    // d_in[2] = value: unused by the reference outputs (attn, scores)
    const int*   mask = (const int*)d_in[3];

    float* out    = (float*)d_out;
    float* attn   = out;                                   // (B,H,S,S)
    float* scores = out + (size_t)B_ * H_ * S_ * S_;       // (B,H,S,S)

    mha_fused<<<dim3(NWG), dim3(256), 0, stream>>>(q, k, mask, attn, scores);
}